// Round 2
// baseline (381.397 us; speedup 1.0000x reference)
//
#include <hip/hip_runtime.h>
#include <stdint.h>
#include <stddef.h>

#define CDIM 1024
#define HWD  1024   // 32*32
#define TD   16
#define BD   2
#define NH   16
#define DHD  64

typedef __attribute__((ext_vector_type(8))) short bf16x8;
typedef __attribute__((ext_vector_type(4))) short bf16x4;
typedef __attribute__((ext_vector_type(4))) float f32x4;

static __device__ __forceinline__ short f2bf(float f) {
  uint32_t u = __builtin_bit_cast(uint32_t, f);
  uint32_t r = (u + 0x7FFFu + ((u >> 16) & 1u)) >> 16;
  return (short)(uint16_t)r;
}
static __device__ __forceinline__ float bf2f(short s) {
  return __builtin_bit_cast(float, (uint32_t)((uint16_t)s) << 16);
}

static __device__ __forceinline__ void gl_lds16(const short* g, short* l) {
  __builtin_amdgcn_global_load_lds((const __attribute__((address_space(1))) unsigned int*)g,
                                   (__attribute__((address_space(3))) unsigned int*)l,
                                   16, 0, 0);
}

// ---------------- K0: cast Wv -> bf16 ----------------
__global__ void k_cast_w(const float* __restrict__ W, short* __restrict__ Wb) {
  int i = (blockIdx.x * 256 + threadIdx.x) * 4;
  f32x4 v = *(const f32x4*)&W[i];
  Wb[i + 0] = f2bf(v[0]);
  Wb[i + 1] = f2bf(v[1]);
  Wb[i + 2] = f2bf(v[2]);
  Wb[i + 3] = f2bf(v[3]);
}

// ---------------- K1: LayerNorm over C + transposed bf16 write ----------------
// grid (HW/64, B*T), block 256. Block owns 64 input pixels (p0..p0+63).
// Writes xnT[bt][q][c] where q = transpose32x32(p)  (this also implements the
// reference's net spatial transpose: out pixel (h,w) uses input pixel (w,h)).
__global__ void k_ln_t(const float* __restrict__ x, const float* __restrict__ lnw,
                       const float* __restrict__ lnb, short* __restrict__ xnT) {
  int bt = blockIdx.y;
  int p0 = blockIdx.x * 64;
  int tid = threadIdx.x;
  int pl = tid & 63;   // pixel lane
  int cq = tid >> 6;   // c-quarter
  const float* xs = x + (size_t)bt * CDIM * HWD;

  float s = 0.f, s2 = 0.f;
  for (int c = cq * 256; c < cq * 256 + 256; ++c) {
    float v = xs[(size_t)c * HWD + p0 + pl];
    s += v; s2 += v * v;
  }
  __shared__ float red[8][64];
  red[cq][pl] = s;
  red[4 + cq][pl] = s2;
  __syncthreads();
  float st  = red[0][pl] + red[1][pl] + red[2][pl] + red[3][pl];
  float st2 = red[4][pl] + red[5][pl] + red[6][pl] + red[7][pl];
  float mu   = st * (1.0f / CDIM);
  float var  = st2 * (1.0f / CDIM) - mu * mu;
  float rstd = rsqrtf(var + 1e-5f);

  __shared__ short tile[64 * 68];  // [64 pixels][64 c] padded to 68 (2-way bank = free)
  short* outB = xnT + (size_t)bt * CDIM * HWD;

  for (int cb = 0; cb < 16; ++cb) {
    #pragma unroll
    for (int cc2 = 0; cc2 < 16; ++cc2) {
      int c = cb * 64 + cq * 16 + cc2;
      float v = xs[(size_t)c * HWD + p0 + pl];
      float xn = (v - mu) * rstd * lnw[c] + lnb[c];
      tile[pl * 68 + cq * 16 + cc2] = f2bf(xn);
    }
    __syncthreads();
    #pragma unroll
    for (int it = 0; it < 2; ++it) {
      int ch = it * 256 + tid;        // 512 chunks of 16B
      int plo = ch >> 3;
      int c8 = (ch & 7) * 8;
      bf16x4 a = *(const bf16x4*)&tile[plo * 68 + c8];
      bf16x4 b = *(const bf16x4*)&tile[plo * 68 + c8 + 4];
      int pq = p0 + plo;
      int q = (pq & 31) * 32 + (pq >> 5);   // 32x32 spatial transpose
      short* dst = outB + (size_t)q * CDIM + cb * 64 + c8;
      *(bf16x4*)dst = a;
      *(bf16x4*)(dst + 4) = b;
    }
    __syncthreads();
  }
}

// ---------------- K2a/K2b: pooled = mean over pixels ----------------
// part[pc][bt][c]: grid (8, 32) block 128 (8 c per thread, bf16x8 loads)
__global__ void k_pool_part(const short* __restrict__ xnT, float* __restrict__ part) {
  int bt = blockIdx.y, pc = blockIdx.x;
  int c8 = threadIdx.x * 8;
  const short* base = xnT + (size_t)bt * CDIM * HWD;
  float s[8] = {};
  for (int p = pc * 128; p < pc * 128 + 128; ++p) {
    bf16x8 v = *(const bf16x8*)&base[(size_t)p * CDIM + c8];
    #pragma unroll
    for (int k = 0; k < 8; ++k) s[k] += bf2f(v[k]);
  }
  float* pr = part + ((size_t)pc * BD * TD + bt) * CDIM + c8;
  #pragma unroll
  for (int k = 0; k < 8; ++k) pr[k] = s[k];
}
// grid (4, 32) block 256
__global__ void k_pool_red(const float* __restrict__ part, float* __restrict__ pooled) {
  int bt = blockIdx.y;
  int c = blockIdx.x * 256 + threadIdx.x;
  float s = 0.f;
  #pragma unroll
  for (int pc = 0; pc < 8; ++pc) s += part[((size_t)pc * BD * TD + bt) * CDIM + c];
  pooled[bt * CDIM + c] = s * (1.0f / HWD);
}

// ---------------- K3: q = pooled @ Wq^T, k = pooled @ Wk^T ----------------
// One wave per output column c; all 32 rows accumulated in registers.
// W read once from HBM; pooled (128 KB) is L2-resident.
// grid (C/4, 2), block 256 (4 waves)
__global__ void k_qk(const float* __restrict__ pooled, const float* __restrict__ Wq,
                     const float* __restrict__ Wk, float* __restrict__ qm,
                     float* __restrict__ km) {
  int z = blockIdx.y;
  int w = threadIdx.x >> 6, lane = threadIdx.x & 63;
  int c = blockIdx.x * 4 + w;
  const float* W = z ? Wk : Wq;
  float* outp = z ? km : qm;
  const float* wr = W + (size_t)c * CDIM;
  float acc[32];
  #pragma unroll
  for (int r = 0; r < 32; ++r) acc[r] = 0.f;
  #pragma unroll
  for (int kc = 0; kc < 4; ++kc) {
    int k4 = kc * 256 + lane * 4;
    f32x4 w4 = *(const f32x4*)&wr[k4];
    #pragma unroll
    for (int r = 0; r < 32; ++r) {
      f32x4 p4 = *(const f32x4*)&pooled[(size_t)r * CDIM + k4];
      acc[r] += w4[0] * p4[0] + w4[1] * p4[1] + w4[2] * p4[2] + w4[3] * p4[3];
    }
  }
  #pragma unroll
  for (int r = 0; r < 32; ++r) {
    float v = acc[r];
    #pragma unroll
    for (int off = 32; off; off >>= 1) v += __shfl_down(v, off, 64);
    if (lane == 0) outp[(size_t)r * CDIM + c] = v;
  }
}

// ---------------- K4: attention softmax ----------------
// grid B*NH, block 256 (thread = (s,t) pair)
__global__ void k_attn(const float* __restrict__ qm, const float* __restrict__ km,
                       float* __restrict__ attn) {
  int bg = blockIdx.x;            // b*16 + g
  int b = bg >> 4, g = bg & 15;
  int s = threadIdx.x >> 4, t = threadIdx.x & 15;
  const float* qr = qm + (size_t)(b * TD + s) * CDIM + g * DHD;
  const float* kr = km + (size_t)(b * TD + t) * CDIM + g * DHD;
  float d = 0.f;
  #pragma unroll
  for (int i = 0; i < DHD; ++i) d += qr[i] * kr[i];
  d *= 0.125f;  // dh^-0.5
  float m = d;
  #pragma unroll
  for (int off = 8; off; off >>= 1) m = fmaxf(m, __shfl_xor(m, off, 16));
  float e = __expf(d - m);
  float sum = e;
  #pragma unroll
  for (int off = 8; off; off >>= 1) sum += __shfl_xor(sum, off, 16);
  attn[(size_t)bg * 256 + s * 16 + t] = e / sum;
}

// ---------------- K5: V-GEMM  vp[bt][c][q] = sum_c' Wv[c,c'] * xnT[bt][q][c'] ----------------
// m97 structure: 128x128 tile, BK=32, 4 waves, global_load_lds w16, mfma 16x16x32 bf16
// grid (8, 8, 32), block 256
__global__ __launch_bounds__(256) void k_vgemm(const short* __restrict__ Wb,
                                               const short* __restrict__ xnT,
                                               short* __restrict__ vp) {
  int bt = blockIdx.z;
  int m0 = blockIdx.y * 128;   // output channel c
  int n0 = blockIdx.x * 128;   // pixel q
  const short* A = Wb;                                   // [C][C] k-contig
  const short* Bm = xnT + (size_t)bt * CDIM * HWD;       // [q][c'] k-contig
  __shared__ __align__(16) short lA[128 * 32];
  __shared__ __align__(16) short lB[128 * 32];
  int tid = threadIdx.x;
  int lane = tid & 63;
  int wid = tid >> 6;
  int wr = (wid >> 1) * 64;
  int wc = (wid & 1) * 64;
  f32x4 acc[4][4] = {};

  int sm = tid >> 2, sk = (tid & 3) * 8;                 // staging: row, k-chunk
  const short* gA = A + (size_t)(m0 + sm) * CDIM + sk;
  const short* gB = Bm + (size_t)(n0 + sm) * CDIM + sk;
  short* dA = &lA[tid * 8];
  short* dB = &lB[tid * 8];
  int fr = lane & 15, fk = (lane >> 4) * 8;

  for (int kt = 0; kt < CDIM / 32; ++kt) {
    __syncthreads();
    gl_lds16(gA + kt * 32, dA);
    gl_lds16(gA + kt * 32 + (size_t)64 * CDIM, dA + 64 * 32);
    gl_lds16(gB + kt * 32, dB);
    gl_lds16(gB + kt * 32 + (size_t)64 * CDIM, dB + 64 * 32);
    __syncthreads();
    bf16x8 af[4], bfr[4];
    #pragma unroll
    for (int mi = 0; mi < 4; ++mi)
      af[mi] = *(const bf16x8*)&lA[(wr + mi * 16 + fr) * 32 + fk];
    #pragma unroll
    for (int ni = 0; ni < 4; ++ni)
      bfr[ni] = *(const bf16x8*)&lB[(wc + ni * 16 + fr) * 32 + fk];
    #pragma unroll
    for (int mi = 0; mi < 4; ++mi)
      #pragma unroll
      for (int ni = 0; ni < 4; ++ni)
        acc[mi][ni] = __builtin_amdgcn_mfma_f32_16x16x32_bf16(af[mi], bfr[ni], acc[mi][ni], 0, 0, 0);
  }

  short* outB = vp + (size_t)bt * CDIM * HWD;
  int cr = lane >> 4;
  #pragma unroll
  for (int mi = 0; mi < 4; ++mi)
    #pragma unroll
    for (int ni = 0; ni < 4; ++ni)
      #pragma unroll
      for (int r = 0; r < 4; ++r) {
        int row = m0 + wr + mi * 16 + cr * 4 + r;   // c
        int col = n0 + wc + ni * 16 + fr;           // q
        outB[(size_t)row * HWD + col] = f2bf(acc[mi][ni][r]);
      }
}

// ---------------- K6: T-mix  out[b,s,c,p] = sum_t attn[b,g(c),s,t] * vp[b,t,c,p] ----------------
// v2: stage the 16 vp t-rows (32 KB bf16) in LDS; s in two halves of 8 so the
// live accumulator is f32x4 acc[8] (32 VGPRs, statically indexed — no spill).
// grid (C, B), block 256
__global__ __launch_bounds__(256) void k_mix(const short* __restrict__ vp,
                                             const float* __restrict__ attn,
                                             float* __restrict__ out) {
  int c = blockIdx.x;
  int b = blockIdx.y;
  int g = c >> 6;
  __shared__ __align__(16) short vpl[TD * HWD];  // 32 KB
  __shared__ float at[256];
  int tid = threadIdx.x;
  at[tid] = attn[(size_t)(b * NH + g) * 256 + tid];
  #pragma unroll
  for (int j = 0; j < 8; ++j) {
    int chunk = j * 256 + tid;
    int t = chunk >> 7, qc = chunk & 127;
    bf16x8 v = *(const bf16x8*)&vp[((size_t)(b * TD + t) * CDIM + c) * HWD + qc * 8];
    *(bf16x8*)&vpl[t * HWD + qc * 8] = v;
  }
  __syncthreads();
  int p = tid * 4;
  #pragma unroll
  for (int sh = 0; sh < 2; ++sh) {
    f32x4 acc[8] = {};
    #pragma unroll
    for (int t = 0; t < TD; ++t) {
      bf16x4 v4 = *(const bf16x4*)&vpl[t * HWD + p];
      f32x4 vf = {bf2f(v4[0]), bf2f(v4[1]), bf2f(v4[2]), bf2f(v4[3])};
      #pragma unroll
      for (int s8 = 0; s8 < 8; ++s8) {
        float a = at[(sh * 8 + s8) * 16 + t];
        acc[s8] += a * vf;
      }
    }
    #pragma unroll
    for (int s8 = 0; s8 < 8; ++s8) {
      int s = sh * 8 + s8;
      *(f32x4*)&out[((size_t)(b * TD + s) * CDIM + c) * HWD + p] = acc[s8];
    }
  }
}

// ---------------- launch ----------------
extern "C" void kernel_launch(void* const* d_in, const int* in_sizes, int n_in,
                              void* d_out, int out_size, void* d_ws, size_t ws_size,
                              hipStream_t stream) {
  const float* x   = (const float*)d_in[0];
  const float* lnw = (const float*)d_in[1];
  const float* lnb = (const float*)d_in[2];
  const float* Wq  = (const float*)d_in[3];
  const float* Wk  = (const float*)d_in[4];
  const float* Wv  = (const float*)d_in[5];
  float* out = (float*)d_out;

  char* ws = (char*)d_ws;
  const size_t XNT_OFF   = 0;                       // bf16 [32][1024 q][1024 c]  64 MiB
  const size_t VP_OFF    = XNT_OFF + 67108864;      // bf16 [32][1024 c][1024 q]  64 MiB
  const size_t WB_OFF    = VP_OFF + 67108864;       // bf16 Wv                    2 MiB
  const size_t POOLP_OFF = WB_OFF + 2097152;        // f32 [8][32][1024]          1 MiB
  const size_t POOL_OFF  = POOLP_OFF + 1048576;     // f32 [32][1024]
  const size_t QM_OFF    = POOL_OFF + 131072;
  const size_t KM_OFF    = QM_OFF + 131072;
  const size_t ATTN_OFF  = KM_OFF + 131072;         // f32 [32][16][16]

  short* xnT    = (short*)(ws + XNT_OFF);
  short* vp     = (short*)(ws + VP_OFF);
  short* Wb     = (short*)(ws + WB_OFF);
  float* poolp  = (float*)(ws + POOLP_OFF);
  float* pooled = (float*)(ws + POOL_OFF);
  float* qm     = (float*)(ws + QM_OFF);
  float* km     = (float*)(ws + KM_OFF);
  float* attn   = (float*)(ws + ATTN_OFF);

  k_cast_w<<<dim3(1024), 256, 0, stream>>>(Wv, Wb);
  k_ln_t<<<dim3(16, 32), 256, 0, stream>>>(x, lnw, lnb, xnT);
  k_pool_part<<<dim3(8, 32), 128, 0, stream>>>(xnT, poolp);
  k_pool_red<<<dim3(4, 32), 256, 0, stream>>>(poolp, pooled);
  k_qk<<<dim3(256, 2), 256, 0, stream>>>(pooled, Wq, Wk, qm, km);
  k_attn<<<dim3(32), 256, 0, stream>>>(qm, km, attn);
  k_vgemm<<<dim3(8, 8, 32), 256, 0, stream>>>(Wb, xnT, vp);
  k_mix<<<dim3(1024, 2), 256, 0, stream>>>(vp, attn, out);
}

// Round 3
// 238.323 us; speedup vs baseline: 1.6003x; 1.6003x over previous
//
#include <hip/hip_runtime.h>
#include <stdint.h>
#include <stddef.h>

#define CDIM 1024
#define HWD  1024   // 32*32
#define TD   16
#define BD   2
#define NH   16
#define DHD  64

typedef __attribute__((ext_vector_type(8))) short bf16x8;
typedef __attribute__((ext_vector_type(4))) short bf16x4;
typedef __attribute__((ext_vector_type(4))) float f32x4;

static __device__ __forceinline__ short f2bf(float f) {
  uint32_t u = __builtin_bit_cast(uint32_t, f);
  uint32_t r = (u + 0x7FFFu + ((u >> 16) & 1u)) >> 16;
  return (short)(uint16_t)r;
}
static __device__ __forceinline__ float bf2f(short s) {
  return __builtin_bit_cast(float, (uint32_t)((uint16_t)s) << 16);
}

static __device__ __forceinline__ void gl_lds16(const short* g, short* l) {
  __builtin_amdgcn_global_load_lds((const __attribute__((address_space(1))) unsigned int*)g,
                                   (__attribute__((address_space(3))) unsigned int*)l,
                                   16, 0, 0);
}

// ---------------- K0: cast f32 -> bf16 (used for Wv, Wq, Wk) ----------------
__global__ void k_cast_w(const float* __restrict__ W, short* __restrict__ Wb) {
  int i = (blockIdx.x * 256 + threadIdx.x) * 4;
  f32x4 v = *(const f32x4*)&W[i];
  Wb[i + 0] = f2bf(v[0]);
  Wb[i + 1] = f2bf(v[1]);
  Wb[i + 2] = f2bf(v[2]);
  Wb[i + 3] = f2bf(v[3]);
}

// ---------------- K1: LayerNorm over C + transposed bf16 write ----------------
// grid (HW/64, B*T), block 256. Block owns 64 input pixels (p0..p0+63).
// Writes xnT[bt][q][c] where q = transpose32x32(p)  (this also implements the
// reference's net spatial transpose: out pixel (h,w) uses input pixel (w,h)).
__global__ void k_ln_t(const float* __restrict__ x, const float* __restrict__ lnw,
                       const float* __restrict__ lnb, short* __restrict__ xnT) {
  int bt = blockIdx.y;
  int p0 = blockIdx.x * 64;
  int tid = threadIdx.x;
  int pl = tid & 63;   // pixel lane
  int cq = tid >> 6;   // c-quarter
  const float* xs = x + (size_t)bt * CDIM * HWD;

  float s = 0.f, s2 = 0.f;
  for (int c = cq * 256; c < cq * 256 + 256; ++c) {
    float v = xs[(size_t)c * HWD + p0 + pl];
    s += v; s2 += v * v;
  }
  __shared__ float red[8][64];
  red[cq][pl] = s;
  red[4 + cq][pl] = s2;
  __syncthreads();
  float st  = red[0][pl] + red[1][pl] + red[2][pl] + red[3][pl];
  float st2 = red[4][pl] + red[5][pl] + red[6][pl] + red[7][pl];
  float mu   = st * (1.0f / CDIM);
  float var  = st2 * (1.0f / CDIM) - mu * mu;
  float rstd = rsqrtf(var + 1e-5f);

  __shared__ short tile[64 * 68];  // [64 pixels][64 c] padded to 68 (2-way bank = free)
  short* outB = xnT + (size_t)bt * CDIM * HWD;

  for (int cb = 0; cb < 16; ++cb) {
    #pragma unroll
    for (int cc2 = 0; cc2 < 16; ++cc2) {
      int c = cb * 64 + cq * 16 + cc2;
      float v = xs[(size_t)c * HWD + p0 + pl];
      float xn = (v - mu) * rstd * lnw[c] + lnb[c];
      tile[pl * 68 + cq * 16 + cc2] = f2bf(xn);
    }
    __syncthreads();
    #pragma unroll
    for (int it = 0; it < 2; ++it) {
      int ch = it * 256 + tid;        // 512 chunks of 16B
      int plo = ch >> 3;
      int c8 = (ch & 7) * 8;
      bf16x4 a = *(const bf16x4*)&tile[plo * 68 + c8];
      bf16x4 b = *(const bf16x4*)&tile[plo * 68 + c8 + 4];
      int pq = p0 + plo;
      int q = (pq & 31) * 32 + (pq >> 5);   // 32x32 spatial transpose
      short* dst = outB + (size_t)q * CDIM + cb * 64 + c8;
      *(bf16x4*)dst = a;
      *(bf16x4*)(dst + 4) = b;
    }
    __syncthreads();
  }
}

// ---------------- K2a/K2b: pooled = mean over pixels ----------------
// part[pc][bt][c]: grid (8, 32) block 128 (8 c per thread, bf16x8 loads)
__global__ void k_pool_part(const short* __restrict__ xnT, float* __restrict__ part) {
  int bt = blockIdx.y, pc = blockIdx.x;
  int c8 = threadIdx.x * 8;
  const short* base = xnT + (size_t)bt * CDIM * HWD;
  float s[8] = {};
  for (int p = pc * 128; p < pc * 128 + 128; ++p) {
    bf16x8 v = *(const bf16x8*)&base[(size_t)p * CDIM + c8];
    #pragma unroll
    for (int k = 0; k < 8; ++k) s[k] += bf2f(v[k]);
  }
  float* pr = part + ((size_t)pc * BD * TD + bt) * CDIM + c8;
  #pragma unroll
  for (int k = 0; k < 8; ++k) pr[k] = s[k];
}
// grid (4, 32) block 256; writes f32 (unused downstream now) + bf16 for MFMA qk
__global__ void k_pool_red(const float* __restrict__ part, float* __restrict__ pooled,
                           short* __restrict__ pooledb) {
  int bt = blockIdx.y;
  int c = blockIdx.x * 256 + threadIdx.x;
  float s = 0.f;
  #pragma unroll
  for (int pc = 0; pc < 8; ++pc) s += part[((size_t)pc * BD * TD + bt) * CDIM + c];
  float m = s * (1.0f / HWD);
  pooled[bt * CDIM + c] = m;
  pooledb[bt * CDIM + c] = f2bf(m);
}

// ---------------- K3: q|k = pooled @ [Wq;Wk]^T via MFMA ----------------
// M=32 (bt rows), N=2048 (Wq cols then Wk cols), K=1024. bf16 inputs.
// grid 16 (N-tiles of 128), block 256 (4 waves, each wave 32 cols x 32 rows).
__global__ __launch_bounds__(256) void k_qk_mfma(const short* __restrict__ Wqkb,
                                                 const short* __restrict__ pooledb,
                                                 float* __restrict__ qm,
                                                 float* __restrict__ km) {
  int n0 = blockIdx.x * 128;
  __shared__ __align__(16) short lA[32 * 32];    // pooledb tile [32 rows][32 k]
  __shared__ __align__(16) short lB[128 * 32];   // W tile [128 cols][32 k]
  int tid = threadIdx.x, lane = tid & 63, wid = tid >> 6;
  int s0 = wid * 128 + lane, s1 = s0 + 64;       // 16B slot ids for lB staging
  int fr = lane & 15, fk = (lane >> 4) * 8;
  f32x4 acc[2][2] = {};

  for (int kt = 0; kt < CDIM / 32; ++kt) {
    int k0 = kt * 32;
    __syncthreads();
    gl_lds16(&Wqkb[(size_t)(n0 + (s0 >> 2)) * CDIM + k0 + (s0 & 3) * 8], &lB[s0 * 8]);
    gl_lds16(&Wqkb[(size_t)(n0 + (s1 >> 2)) * CDIM + k0 + (s1 & 3) * 8], &lB[s1 * 8]);
    if (wid < 2) {
      gl_lds16(&pooledb[(size_t)(tid >> 2) * CDIM + k0 + (tid & 3) * 8], &lA[tid * 8]);
    }
    __syncthreads();
    bf16x8 af[2], bfr[2];
    #pragma unroll
    for (int mi = 0; mi < 2; ++mi)
      af[mi] = *(const bf16x8*)&lA[(mi * 16 + fr) * 32 + fk];
    #pragma unroll
    for (int ni = 0; ni < 2; ++ni)
      bfr[ni] = *(const bf16x8*)&lB[(wid * 32 + ni * 16 + fr) * 32 + fk];
    #pragma unroll
    for (int mi = 0; mi < 2; ++mi)
      #pragma unroll
      for (int ni = 0; ni < 2; ++ni)
        acc[mi][ni] = __builtin_amdgcn_mfma_f32_16x16x32_bf16(af[mi], bfr[ni], acc[mi][ni], 0, 0, 0);
  }

  int cr = lane >> 4;
  #pragma unroll
  for (int mi = 0; mi < 2; ++mi)
    #pragma unroll
    for (int ni = 0; ni < 2; ++ni)
      #pragma unroll
      for (int rr = 0; rr < 4; ++rr) {
        int row = mi * 16 + cr * 4 + rr;              // bt row 0..31
        int col = n0 + wid * 32 + ni * 16 + fr;       // 0..2047
        float v = acc[mi][ni][rr];
        if (col < 1024) qm[(size_t)row * CDIM + col] = v;
        else            km[(size_t)row * CDIM + col - 1024] = v;
      }
}

// ---------------- K4: attention softmax ----------------
// grid B*NH, block 256 (thread = (s,t) pair)
__global__ void k_attn(const float* __restrict__ qm, const float* __restrict__ km,
                       float* __restrict__ attn) {
  int bg = blockIdx.x;            // b*16 + g
  int b = bg >> 4, g = bg & 15;
  int s = threadIdx.x >> 4, t = threadIdx.x & 15;
  const float* qr = qm + (size_t)(b * TD + s) * CDIM + g * DHD;
  const float* kr = km + (size_t)(b * TD + t) * CDIM + g * DHD;
  float d = 0.f;
  #pragma unroll
  for (int i = 0; i < DHD; ++i) d += qr[i] * kr[i];
  d *= 0.125f;  // dh^-0.5
  float m = d;
  #pragma unroll
  for (int off = 8; off; off >>= 1) m = fmaxf(m, __shfl_xor(m, off, 16));
  float e = __expf(d - m);
  float sum = e;
  #pragma unroll
  for (int off = 8; off; off >>= 1) sum += __shfl_xor(sum, off, 16);
  attn[(size_t)bg * 256 + s * 16 + t] = e / sum;
}

// ---------------- K5: V-GEMM  vp[bt][c][q] = sum_c' Wv[c,c'] * xnT[bt][q][c'] ----------------
// m97 structure: 128x128 tile, BK=32, 4 waves, global_load_lds w16, mfma 16x16x32 bf16
// grid (8, 8, 32), block 256
__global__ __launch_bounds__(256) void k_vgemm(const short* __restrict__ Wb,
                                               const short* __restrict__ xnT,
                                               short* __restrict__ vp) {
  int bt = blockIdx.z;
  int m0 = blockIdx.y * 128;   // output channel c
  int n0 = blockIdx.x * 128;   // pixel q
  const short* A = Wb;                                   // [C][C] k-contig
  const short* Bm = xnT + (size_t)bt * CDIM * HWD;       // [q][c'] k-contig
  __shared__ __align__(16) short lA[128 * 32];
  __shared__ __align__(16) short lB[128 * 32];
  int tid = threadIdx.x;
  int lane = tid & 63;
  int wid = tid >> 6;
  int wr = (wid >> 1) * 64;
  int wc = (wid & 1) * 64;
  f32x4 acc[4][4] = {};

  int sm = tid >> 2, sk = (tid & 3) * 8;                 // staging: row, k-chunk
  const short* gA = A + (size_t)(m0 + sm) * CDIM + sk;
  const short* gB = Bm + (size_t)(n0 + sm) * CDIM + sk;
  short* dA = &lA[tid * 8];
  short* dB = &lB[tid * 8];
  int fr = lane & 15, fk = (lane >> 4) * 8;

  for (int kt = 0; kt < CDIM / 32; ++kt) {
    __syncthreads();
    gl_lds16(gA + kt * 32, dA);
    gl_lds16(gA + kt * 32 + (size_t)64 * CDIM, dA + 64 * 32);
    gl_lds16(gB + kt * 32, dB);
    gl_lds16(gB + kt * 32 + (size_t)64 * CDIM, dB + 64 * 32);
    __syncthreads();
    bf16x8 af[4], bfr[4];
    #pragma unroll
    for (int mi = 0; mi < 4; ++mi)
      af[mi] = *(const bf16x8*)&lA[(wr + mi * 16 + fr) * 32 + fk];
    #pragma unroll
    for (int ni = 0; ni < 4; ++ni)
      bfr[ni] = *(const bf16x8*)&lB[(wc + ni * 16 + fr) * 32 + fk];
    #pragma unroll
    for (int mi = 0; mi < 4; ++mi)
      #pragma unroll
      for (int ni = 0; ni < 4; ++ni)
        acc[mi][ni] = __builtin_amdgcn_mfma_f32_16x16x32_bf16(af[mi], bfr[ni], acc[mi][ni], 0, 0, 0);
  }

  short* outB = vp + (size_t)bt * CDIM * HWD;
  int cr = lane >> 4;
  #pragma unroll
  for (int mi = 0; mi < 4; ++mi)
    #pragma unroll
    for (int ni = 0; ni < 4; ++ni)
      #pragma unroll
      for (int r = 0; r < 4; ++r) {
        int row = m0 + wr + mi * 16 + cr * 4 + r;   // c
        int col = n0 + wc + ni * 16 + fr;           // q
        outB[(size_t)row * HWD + col] = f2bf(acc[mi][ni][r]);
      }
}

// ---------------- K6: T-mix  out[b,s,c,p] = sum_t attn[b,g(c),s,t] * vp[b,t,c,p] ----------------
// v2: stage the 16 vp t-rows (32 KB bf16) in LDS; s in two halves of 8 so the
// live accumulator is f32x4 acc[8] (32 VGPRs, statically indexed — no spill).
// grid (C, B), block 256
__global__ __launch_bounds__(256) void k_mix(const short* __restrict__ vp,
                                             const float* __restrict__ attn,
                                             float* __restrict__ out) {
  int c = blockIdx.x;
  int b = blockIdx.y;
  int g = c >> 6;
  __shared__ __align__(16) short vpl[TD * HWD];  // 32 KB
  __shared__ float at[256];
  int tid = threadIdx.x;
  at[tid] = attn[(size_t)(b * NH + g) * 256 + tid];
  #pragma unroll
  for (int j = 0; j < 8; ++j) {
    int chunk = j * 256 + tid;
    int t = chunk >> 7, qc = chunk & 127;
    bf16x8 v = *(const bf16x8*)&vp[((size_t)(b * TD + t) * CDIM + c) * HWD + qc * 8];
    *(bf16x8*)&vpl[t * HWD + qc * 8] = v;
  }
  __syncthreads();
  int p = tid * 4;
  #pragma unroll
  for (int sh = 0; sh < 2; ++sh) {
    f32x4 acc[8] = {};
    #pragma unroll
    for (int t = 0; t < TD; ++t) {
      bf16x4 v4 = *(const bf16x4*)&vpl[t * HWD + p];
      f32x4 vf = {bf2f(v4[0]), bf2f(v4[1]), bf2f(v4[2]), bf2f(v4[3])};
      #pragma unroll
      for (int s8 = 0; s8 < 8; ++s8) {
        float a = at[(sh * 8 + s8) * 16 + t];
        acc[s8] += a * vf;
      }
    }
    #pragma unroll
    for (int s8 = 0; s8 < 8; ++s8) {
      int s = sh * 8 + s8;
      *(f32x4*)&out[((size_t)(b * TD + s) * CDIM + c) * HWD + p] = acc[s8];
    }
  }
}

// ---------------- launch ----------------
extern "C" void kernel_launch(void* const* d_in, const int* in_sizes, int n_in,
                              void* d_out, int out_size, void* d_ws, size_t ws_size,
                              hipStream_t stream) {
  const float* x   = (const float*)d_in[0];
  const float* lnw = (const float*)d_in[1];
  const float* lnb = (const float*)d_in[2];
  const float* Wq  = (const float*)d_in[3];
  const float* Wk  = (const float*)d_in[4];
  const float* Wv  = (const float*)d_in[5];
  float* out = (float*)d_out;

  char* ws = (char*)d_ws;
  const size_t XNT_OFF   = 0;                       // bf16 [32][1024 q][1024 c]  64 MiB
  const size_t VP_OFF    = XNT_OFF + 67108864;      // bf16 [32][1024 c][1024 q]  64 MiB
  const size_t WB_OFF    = VP_OFF + 67108864;       // bf16 Wv                    2 MiB
  const size_t WQKB_OFF  = WB_OFF + 2097152;        // bf16 [Wq;Wk]               4 MiB
  const size_t POOLP_OFF = WQKB_OFF + 4194304;      // f32 [8][32][1024]          1 MiB
  const size_t POOL_OFF  = POOLP_OFF + 1048576;     // f32 [32][1024]
  const size_t POOLB_OFF = POOL_OFF + 131072;       // bf16 [32][1024]
  const size_t QM_OFF    = POOLB_OFF + 65536;
  const size_t KM_OFF    = QM_OFF + 131072;
  const size_t ATTN_OFF  = KM_OFF + 131072;         // f32 [32][16][16]

  short* xnT    = (short*)(ws + XNT_OFF);
  short* vp     = (short*)(ws + VP_OFF);
  short* Wb     = (short*)(ws + WB_OFF);
  short* Wqkb   = (short*)(ws + WQKB_OFF);
  float* poolp  = (float*)(ws + POOLP_OFF);
  float* pooled = (float*)(ws + POOL_OFF);
  short* poolb  = (short*)(ws + POOLB_OFF);
  float* qm     = (float*)(ws + QM_OFF);
  float* km     = (float*)(ws + KM_OFF);
  float* attn   = (float*)(ws + ATTN_OFF);

  k_cast_w<<<dim3(1024), 256, 0, stream>>>(Wv, Wb);
  k_cast_w<<<dim3(1024), 256, 0, stream>>>(Wq, Wqkb);
  k_cast_w<<<dim3(1024), 256, 0, stream>>>(Wk, Wqkb + 1048576);
  k_ln_t<<<dim3(16, 32), 256, 0, stream>>>(x, lnw, lnb, xnT);
  k_pool_part<<<dim3(8, 32), 128, 0, stream>>>(xnT, poolp);
  k_pool_red<<<dim3(4, 32), 256, 0, stream>>>(poolp, pooled, poolb);
  k_qk_mfma<<<dim3(16), 256, 0, stream>>>(Wqkb, poolb, qm, km);
  k_attn<<<dim3(32), 256, 0, stream>>>(qm, km, attn);
  k_vgemm<<<dim3(8, 8, 32), 256, 0, stream>>>(Wb, xnT, vp);
  k_mix<<<dim3(1024, 2), 256, 0, stream>>>(vp, attn, out);
}

// Round 4
// 226.577 us; speedup vs baseline: 1.6833x; 1.0518x over previous
//
#include <hip/hip_runtime.h>
#include <stdint.h>
#include <stddef.h>

#define CDIM 1024
#define HWD  1024   // 32*32
#define TD   16
#define BD   2
#define NH   16
#define DHD  64

typedef __attribute__((ext_vector_type(8))) short bf16x8;
typedef __attribute__((ext_vector_type(4))) short bf16x4;
typedef __attribute__((ext_vector_type(4))) float f32x4;

static __device__ __forceinline__ short f2bf(float f) {
  uint32_t u = __builtin_bit_cast(uint32_t, f);
  uint32_t r = (u + 0x7FFFu + ((u >> 16) & 1u)) >> 16;
  return (short)(uint16_t)r;
}
static __device__ __forceinline__ float bf2f(short s) {
  return __builtin_bit_cast(float, (uint32_t)((uint16_t)s) << 16);
}

static __device__ __forceinline__ void gl_lds16(const short* g, short* l) {
  __builtin_amdgcn_global_load_lds((const __attribute__((address_space(1))) unsigned int*)g,
                                   (__attribute__((address_space(3))) unsigned int*)l,
                                   16, 0, 0);
}

// ---------------- K0: cast f32 -> bf16 (used for Wv, Wq, Wk) ----------------
__global__ void k_cast_w(const float* __restrict__ W, short* __restrict__ Wb) {
  int i = (blockIdx.x * 256 + threadIdx.x) * 4;
  f32x4 v = *(const f32x4*)&W[i];
  Wb[i + 0] = f2bf(v[0]);
  Wb[i + 1] = f2bf(v[1]);
  Wb[i + 2] = f2bf(v[2]);
  Wb[i + 3] = f2bf(v[3]);
}

// ---------------- K1: LayerNorm over C + transposed bf16 write ----------------
__global__ void k_ln_t(const float* __restrict__ x, const float* __restrict__ lnw,
                       const float* __restrict__ lnb, short* __restrict__ xnT) {
  int bt = blockIdx.y;
  int p0 = blockIdx.x * 64;
  int tid = threadIdx.x;
  int pl = tid & 63;   // pixel lane
  int cq = tid >> 6;   // c-quarter
  const float* xs = x + (size_t)bt * CDIM * HWD;

  float s = 0.f, s2 = 0.f;
  for (int c = cq * 256; c < cq * 256 + 256; ++c) {
    float v = xs[(size_t)c * HWD + p0 + pl];
    s += v; s2 += v * v;
  }
  __shared__ float red[8][64];
  red[cq][pl] = s;
  red[4 + cq][pl] = s2;
  __syncthreads();
  float st  = red[0][pl] + red[1][pl] + red[2][pl] + red[3][pl];
  float st2 = red[4][pl] + red[5][pl] + red[6][pl] + red[7][pl];
  float mu   = st * (1.0f / CDIM);
  float var  = st2 * (1.0f / CDIM) - mu * mu;
  float rstd = rsqrtf(var + 1e-5f);

  __shared__ short tile[64 * 68];
  short* outB = xnT + (size_t)bt * CDIM * HWD;

  for (int cb = 0; cb < 16; ++cb) {
    #pragma unroll
    for (int cc2 = 0; cc2 < 16; ++cc2) {
      int c = cb * 64 + cq * 16 + cc2;
      float v = xs[(size_t)c * HWD + p0 + pl];
      float xn = (v - mu) * rstd * lnw[c] + lnb[c];
      tile[pl * 68 + cq * 16 + cc2] = f2bf(xn);
    }
    __syncthreads();
    #pragma unroll
    for (int it = 0; it < 2; ++it) {
      int ch = it * 256 + tid;
      int plo = ch >> 3;
      int c8 = (ch & 7) * 8;
      bf16x4 a = *(const bf16x4*)&tile[plo * 68 + c8];
      bf16x4 b = *(const bf16x4*)&tile[plo * 68 + c8 + 4];
      int pq = p0 + plo;
      int q = (pq & 31) * 32 + (pq >> 5);   // 32x32 spatial transpose
      short* dst = outB + (size_t)q * CDIM + cb * 64 + c8;
      *(bf16x4*)dst = a;
      *(bf16x4*)(dst + 4) = b;
    }
    __syncthreads();
  }
}

// ---------------- K2a/K2b: pooled = mean over pixels ----------------
__global__ void k_pool_part(const short* __restrict__ xnT, float* __restrict__ part) {
  int bt = blockIdx.y, pc = blockIdx.x;
  int c8 = threadIdx.x * 8;
  const short* base = xnT + (size_t)bt * CDIM * HWD;
  float s[8] = {};
  for (int p = pc * 128; p < pc * 128 + 128; ++p) {
    bf16x8 v = *(const bf16x8*)&base[(size_t)p * CDIM + c8];
    #pragma unroll
    for (int k = 0; k < 8; ++k) s[k] += bf2f(v[k]);
  }
  float* pr = part + ((size_t)pc * BD * TD + bt) * CDIM + c8;
  #pragma unroll
  for (int k = 0; k < 8; ++k) pr[k] = s[k];
}
__global__ void k_pool_red(const float* __restrict__ part, float* __restrict__ pooled,
                           short* __restrict__ pooledb) {
  int bt = blockIdx.y;
  int c = blockIdx.x * 256 + threadIdx.x;
  float s = 0.f;
  #pragma unroll
  for (int pc = 0; pc < 8; ++pc) s += part[((size_t)pc * BD * TD + bt) * CDIM + c];
  float m = s * (1.0f / HWD);
  pooled[bt * CDIM + c] = m;
  pooledb[bt * CDIM + c] = f2bf(m);
}

// ---------------- K3: q|k = pooled @ [Wq;Wk]^T via MFMA ----------------
__global__ __launch_bounds__(256) void k_qk_mfma(const short* __restrict__ Wqkb,
                                                 const short* __restrict__ pooledb,
                                                 float* __restrict__ qm,
                                                 float* __restrict__ km) {
  int n0 = blockIdx.x * 128;
  __shared__ __align__(16) short lA[32 * 32];
  __shared__ __align__(16) short lB[128 * 32];
  int tid = threadIdx.x, lane = tid & 63, wid = tid >> 6;
  int s0 = wid * 128 + lane, s1 = s0 + 64;
  int fr = lane & 15, fk = (lane >> 4) * 8;
  f32x4 acc[2][2] = {};

  for (int kt = 0; kt < CDIM / 32; ++kt) {
    int k0 = kt * 32;
    __syncthreads();
    gl_lds16(&Wqkb[(size_t)(n0 + (s0 >> 2)) * CDIM + k0 + (s0 & 3) * 8], &lB[s0 * 8]);
    gl_lds16(&Wqkb[(size_t)(n0 + (s1 >> 2)) * CDIM + k0 + (s1 & 3) * 8], &lB[s1 * 8]);
    if (wid < 2) {
      gl_lds16(&pooledb[(size_t)(tid >> 2) * CDIM + k0 + (tid & 3) * 8], &lA[tid * 8]);
    }
    __syncthreads();
    bf16x8 af[2], bfr[2];
    #pragma unroll
    for (int mi = 0; mi < 2; ++mi)
      af[mi] = *(const bf16x8*)&lA[(mi * 16 + fr) * 32 + fk];
    #pragma unroll
    for (int ni = 0; ni < 2; ++ni)
      bfr[ni] = *(const bf16x8*)&lB[(wid * 32 + ni * 16 + fr) * 32 + fk];
    #pragma unroll
    for (int mi = 0; mi < 2; ++mi)
      #pragma unroll
      for (int ni = 0; ni < 2; ++ni)
        acc[mi][ni] = __builtin_amdgcn_mfma_f32_16x16x32_bf16(af[mi], bfr[ni], acc[mi][ni], 0, 0, 0);
  }

  int cr = lane >> 4;
  #pragma unroll
  for (int mi = 0; mi < 2; ++mi)
    #pragma unroll
    for (int ni = 0; ni < 2; ++ni)
      #pragma unroll
      for (int rr = 0; rr < 4; ++rr) {
        int row = mi * 16 + cr * 4 + rr;
        int col = n0 + wid * 32 + ni * 16 + fr;
        float v = acc[mi][ni][rr];
        if (col < 1024) qm[(size_t)row * CDIM + col] = v;
        else            km[(size_t)row * CDIM + col - 1024] = v;
      }
}

// ---------------- K4: attention softmax ----------------
__global__ void k_attn(const float* __restrict__ qm, const float* __restrict__ km,
                       float* __restrict__ attn) {
  int bg = blockIdx.x;
  int b = bg >> 4, g = bg & 15;
  int s = threadIdx.x >> 4, t = threadIdx.x & 15;
  const float* qr = qm + (size_t)(b * TD + s) * CDIM + g * DHD;
  const float* kr = km + (size_t)(b * TD + t) * CDIM + g * DHD;
  float d = 0.f;
  #pragma unroll
  for (int i = 0; i < DHD; ++i) d += qr[i] * kr[i];
  d *= 0.125f;
  float m = d;
  #pragma unroll
  for (int off = 8; off; off >>= 1) m = fmaxf(m, __shfl_xor(m, off, 16));
  float e = __expf(d - m);
  float sum = e;
  #pragma unroll
  for (int off = 8; off; off >>= 1) sum += __shfl_xor(sum, off, 16);
  attn[(size_t)bg * 256 + s * 16 + t] = e / sum;
}

// ---------------- K5: V-GEMM, 256x256 8-phase (T1+T2+T3+T4+T5) ----------------
// vp[bt][c][q] = sum_c' Wv[c,c'] * xnT[bt][q][c']
// BM=BN=256, BK=64, 512 threads (8 waves = 2M x 4N), LDS 128 KiB double-buffered.
// T2: XOR-swizzle chunk^=(row&7), applied via pre-swizzled GLOBAL source (LDS
// dest linear for global_load_lds) + swizzled ds_read chunk (rule #21).
// T4: one counted vmcnt(2) per K-tile, never 0 in main loop.
__global__ __launch_bounds__(512, 2) void k_vgemm(const short* __restrict__ Wb,
                                                  const short* __restrict__ xnT,
                                                  short* __restrict__ vp) {
  // T1: bijective XCD swizzle (512 blocks, 512%8==0)
  int bid = blockIdx.x;
  int swz = (bid & 7) * 64 + (bid >> 3);
  int bt = swz >> 4;
  int m0 = ((swz >> 2) & 3) * 256;   // output channel tile
  int n0 = (swz & 3) * 256;          // pixel tile
  const short* Bm = xnT + (size_t)bt * CDIM * HWD;

  __shared__ __align__(16) short lA[2][256 * 64];   // 2 x 32 KB
  __shared__ __align__(16) short lB[2][256 * 64];   // 2 x 32 KB

  int tid = threadIdx.x, lane = tid & 63, wid = tid >> 6;
  int wm = wid >> 2, wn = wid & 3;   // wave tile: 128(M) x 64(N)

  // ---- staging addresses (per-lane swizzled global source, linear LDS dest)
  int srow = wid * 8 + (lane >> 3);            // row within 64-row group
  int schunk = (lane & 7) ^ (lane >> 3);       // swizzled 16B chunk
  const short* gA = Wb + (size_t)(m0 + srow) * CDIM + schunk * 8;
  const short* gB = Bm + (size_t)(n0 + srow) * CDIM + schunk * 8;
  int doff = wid * 512 + lane * 8;             // LDS dest (shorts), + p*4096

  // ---- fragment read offsets (swizzled)
  int fr = lane & 15, klane = lane >> 4;
  int c0 = ((klane ^ (fr & 7)) * 8);           // chunk offset (shorts), ks=0; ks=1: ^32
  int rA = (wm * 128 + fr) * 64;               // + mi*16*64
  int rB = (wn * 64 + fr) * 64;                // + ni*16*64

  f32x4 acc[8][4] = {};
  bf16x8 bq[4], af[4];

#define ISSUE(p, kt1, nb)                                                      \
  do {                                                                         \
    gl_lds16(gA + (size_t)(p) * 64 * CDIM + (kt1) * 64, &lA[nb][(p) * 4096 + doff]); \
    gl_lds16(gB + (size_t)(p) * 64 * CDIM + (kt1) * 64, &lB[nb][(p) * 4096 + doff]); \
  } while (0)
#define RDA(mi, ks, b) (*(const bf16x8*)&lA[b][rA + (mi) * 1024 + (c0 ^ ((ks) * 32))])
#define RDB(ni, ks, b) (*(const bf16x8*)&lB[b][rB + (ni) * 1024 + (c0 ^ ((ks) * 32))])

  // prologue: stage tile 0 into buf 0
  ISSUE(0, 0, 0); ISSUE(1, 0, 0); ISSUE(2, 0, 0); ISSUE(3, 0, 0);

  for (int kt = 0; kt < 16; ++kt) {
    int cur = kt & 1, nxt = cur ^ 1;
    bool st = (kt + 1 < 16);
    // ---- phase 0: quad (mh=0, ks=0); rendezvous on tile kt staging
    if (st) {
      ISSUE(0, kt + 1, nxt);
      asm volatile("s_waitcnt vmcnt(2)" ::: "memory");
    } else {
      asm volatile("s_waitcnt vmcnt(0)" ::: "memory");
    }
    __builtin_amdgcn_s_barrier();
    #pragma unroll
    for (int ni = 0; ni < 4; ++ni) bq[ni] = RDB(ni, 0, cur);
    #pragma unroll
    for (int mi = 0; mi < 4; ++mi) af[mi] = RDA(mi, 0, cur);
    __builtin_amdgcn_s_setprio(1);
    #pragma unroll
    for (int mi = 0; mi < 4; ++mi)
      #pragma unroll
      for (int ni = 0; ni < 4; ++ni)
        acc[mi][ni] = __builtin_amdgcn_mfma_f32_16x16x32_bf16(af[mi], bq[ni], acc[mi][ni], 0, 0, 0);
    __builtin_amdgcn_s_setprio(0);
    __builtin_amdgcn_s_barrier();
    // ---- phase 1: quad (mh=1, ks=0)
    #pragma unroll
    for (int mi = 0; mi < 4; ++mi) af[mi] = RDA(4 + mi, 0, cur);
    if (st) ISSUE(1, kt + 1, nxt);
    __builtin_amdgcn_s_barrier();
    __builtin_amdgcn_s_setprio(1);
    #pragma unroll
    for (int mi = 0; mi < 4; ++mi)
      #pragma unroll
      for (int ni = 0; ni < 4; ++ni)
        acc[4 + mi][ni] = __builtin_amdgcn_mfma_f32_16x16x32_bf16(af[mi], bq[ni], acc[4 + mi][ni], 0, 0, 0);
    __builtin_amdgcn_s_setprio(0);
    __builtin_amdgcn_s_barrier();
    // ---- phase 2: quad (mh=0, ks=1)
    #pragma unroll
    for (int ni = 0; ni < 4; ++ni) bq[ni] = RDB(ni, 1, cur);
    #pragma unroll
    for (int mi = 0; mi < 4; ++mi) af[mi] = RDA(mi, 1, cur);
    if (st) ISSUE(2, kt + 1, nxt);
    __builtin_amdgcn_s_barrier();
    __builtin_amdgcn_s_setprio(1);
    #pragma unroll
    for (int mi = 0; mi < 4; ++mi)
      #pragma unroll
      for (int ni = 0; ni < 4; ++ni)
        acc[mi][ni] = __builtin_amdgcn_mfma_f32_16x16x32_bf16(af[mi], bq[ni], acc[mi][ni], 0, 0, 0);
    __builtin_amdgcn_s_setprio(0);
    __builtin_amdgcn_s_barrier();
    // ---- phase 3: quad (mh=1, ks=1)
    #pragma unroll
    for (int mi = 0; mi < 4; ++mi) af[mi] = RDA(4 + mi, 1, cur);
    if (st) ISSUE(3, kt + 1, nxt);
    __builtin_amdgcn_s_barrier();
    __builtin_amdgcn_s_setprio(1);
    #pragma unroll
    for (int mi = 0; mi < 4; ++mi)
      #pragma unroll
      for (int ni = 0; ni < 4; ++ni)
        acc[4 + mi][ni] = __builtin_amdgcn_mfma_f32_16x16x32_bf16(af[mi], bq[ni], acc[4 + mi][ni], 0, 0, 0);
    __builtin_amdgcn_s_setprio(0);
    __builtin_amdgcn_s_barrier();
  }
#undef ISSUE
#undef RDA
#undef RDB

  short* outB = vp + (size_t)bt * CDIM * HWD;
  int cr = lane >> 4;
  #pragma unroll
  for (int mi = 0; mi < 8; ++mi)
    #pragma unroll
    for (int ni = 0; ni < 4; ++ni)
      #pragma unroll
      for (int r = 0; r < 4; ++r) {
        int row = m0 + wm * 128 + mi * 16 + cr * 4 + r;   // c
        int col = n0 + wn * 64 + ni * 16 + fr;            // q
        outB[(size_t)row * HWD + col] = f2bf(acc[mi][ni][r]);
      }
}

// ---------------- K6: T-mix ----------------
__global__ __launch_bounds__(256) void k_mix(const short* __restrict__ vp,
                                             const float* __restrict__ attn,
                                             float* __restrict__ out) {
  int c = blockIdx.x;
  int b = blockIdx.y;
  int g = c >> 6;
  __shared__ __align__(16) short vpl[TD * HWD];  // 32 KB
  __shared__ float at[256];
  int tid = threadIdx.x;
  at[tid] = attn[(size_t)(b * NH + g) * 256 + tid];
  #pragma unroll
  for (int j = 0; j < 8; ++j) {
    int chunk = j * 256 + tid;
    int t = chunk >> 7, qc = chunk & 127;
    bf16x8 v = *(const bf16x8*)&vp[((size_t)(b * TD + t) * CDIM + c) * HWD + qc * 8];
    *(bf16x8*)&vpl[t * HWD + qc * 8] = v;
  }
  __syncthreads();
  int p = tid * 4;
  #pragma unroll
  for (int sh = 0; sh < 2; ++sh) {
    f32x4 acc[8] = {};
    #pragma unroll
    for (int t = 0; t < TD; ++t) {
      bf16x4 v4 = *(const bf16x4*)&vpl[t * HWD + p];
      f32x4 vf = {bf2f(v4[0]), bf2f(v4[1]), bf2f(v4[2]), bf2f(v4[3])};
      #pragma unroll
      for (int s8 = 0; s8 < 8; ++s8) {
        float a = at[(sh * 8 + s8) * 16 + t];
        acc[s8] += a * vf;
      }
    }
    #pragma unroll
    for (int s8 = 0; s8 < 8; ++s8) {
      int s = sh * 8 + s8;
      *(f32x4*)&out[((size_t)(b * TD + s) * CDIM + c) * HWD + p] = acc[s8];
    }
  }
}

// ---------------- launch ----------------
extern "C" void kernel_launch(void* const* d_in, const int* in_sizes, int n_in,
                              void* d_out, int out_size, void* d_ws, size_t ws_size,
                              hipStream_t stream) {
  const float* x   = (const float*)d_in[0];
  const float* lnw = (const float*)d_in[1];
  const float* lnb = (const float*)d_in[2];
  const float* Wq  = (const float*)d_in[3];
  const float* Wk  = (const float*)d_in[4];
  const float* Wv  = (const float*)d_in[5];
  float* out = (float*)d_out;

  char* ws = (char*)d_ws;
  const size_t XNT_OFF   = 0;                       // bf16 [32][1024 q][1024 c]  64 MiB
  const size_t VP_OFF    = XNT_OFF + 67108864;      // bf16 [32][1024 c][1024 q]  64 MiB
  const size_t WB_OFF    = VP_OFF + 67108864;       // bf16 Wv                    2 MiB
  const size_t WQKB_OFF  = WB_OFF + 2097152;        // bf16 [Wq;Wk]               4 MiB
  const size_t POOLP_OFF = WQKB_OFF + 4194304;      // f32 [8][32][1024]          1 MiB
  const size_t POOL_OFF  = POOLP_OFF + 1048576;     // f32 [32][1024]
  const size_t POOLB_OFF = POOL_OFF + 131072;       // bf16 [32][1024]
  const size_t QM_OFF    = POOLB_OFF + 65536;
  const size_t KM_OFF    = QM_OFF + 131072;
  const size_t ATTN_OFF  = KM_OFF + 131072;         // f32 [32][16][16]

  short* xnT    = (short*)(ws + XNT_OFF);
  short* vp     = (short*)(ws + VP_OFF);
  short* Wb     = (short*)(ws + WB_OFF);
  short* Wqkb   = (short*)(ws + WQKB_OFF);
  float* poolp  = (float*)(ws + POOLP_OFF);
  float* pooled = (float*)(ws + POOL_OFF);
  short* poolb  = (short*)(ws + POOLB_OFF);
  float* qm     = (float*)(ws + QM_OFF);
  float* km     = (float*)(ws + KM_OFF);
  float* attn   = (float*)(ws + ATTN_OFF);

  k_cast_w<<<dim3(1024), 256, 0, stream>>>(Wv, Wb);
  k_cast_w<<<dim3(1024), 256, 0, stream>>>(Wq, Wqkb);
  k_cast_w<<<dim3(1024), 256, 0, stream>>>(Wk, Wqkb + 1048576);
  k_ln_t<<<dim3(16, 32), 256, 0, stream>>>(x, lnw, lnb, xnT);
  k_pool_part<<<dim3(8, 32), 128, 0, stream>>>(xnT, poolp);
  k_pool_red<<<dim3(4, 32), 256, 0, stream>>>(poolp, pooled, poolb);
  k_qk_mfma<<<dim3(16), 256, 0, stream>>>(Wqkb, poolb, qm, km);
  k_attn<<<dim3(32), 256, 0, stream>>>(qm, km, attn);
  k_vgemm<<<dim3(512), 512, 0, stream>>>(Wb, xnT, vp);
  k_mix<<<dim3(1024, 2), 256, 0, stream>>>(vp, attn, out);
}